// Round 1
// baseline (314.464 us; speedup 1.0000x reference)
//
#include <hip/hip_runtime.h>

static constexpr int N_ROWS = 524288;
static constexpr int C_COLS = 128;
static constexpr float CLIP_V = 1e-10f;
static constexpr int BLOCKS = 512;
static constexpr int THREADS = 256;

__device__ __forceinline__ float block_reduce_sum(float v) {
    // 64-lane wave reduction (CDNA wave = 64)
    #pragma unroll
    for (int off = 32; off > 0; off >>= 1)
        v += __shfl_down(v, off, 64);
    __shared__ float s[THREADS / 64];
    const int lane = threadIdx.x & 63;
    const int wave = threadIdx.x >> 6;
    if (lane == 0) s[wave] = v;
    __syncthreads();
    if (wave == 0) {
        v = (lane < THREADS / 64) ? s[lane] : 0.0f;
        #pragma unroll
        for (int off = (THREADS / 64) / 2; off > 0; off >>= 1)
            v += __shfl_down(v, off, 64);
    }
    return v; // valid in threadIdx.x == 0
}

__global__ __launch_bounds__(THREADS)
void logloss_partial(const float* __restrict__ inp,
                     const int* __restrict__ tgt,
                     const float* __restrict__ w,
                     float* __restrict__ partial) {
    // stage weight[128] in LDS (512 B)
    __shared__ float ws[C_COLS];
    for (int j = threadIdx.x; j < C_COLS; j += THREADS) ws[j] = w[j];
    __syncthreads();

    const int tid = blockIdx.x * THREADS + threadIdx.x;
    const int stride = gridDim.x * THREADS;
    const int4* __restrict__ t4 = (const int4*)tgt;
    const int n4 = N_ROWS / 4;

    float acc = 0.0f; // accumulates sum of log(clip(x)) * w (negate at the end)
    for (int i = tid; i < n4; i += stride) {
        const int4 t = t4[i];
        const float* row = inp + (size_t)i * (4 * C_COLS);
        // 4 independent gathers -> MLP
        const float x0 = row[0 * C_COLS + t.x];
        const float x1 = row[1 * C_COLS + t.y];
        const float x2 = row[2 * C_COLS + t.z];
        const float x3 = row[3 * C_COLS + t.w];
        acc += __logf(fmaxf(x0, CLIP_V)) * ws[t.x];
        acc += __logf(fmaxf(x1, CLIP_V)) * ws[t.y];
        acc += __logf(fmaxf(x2, CLIP_V)) * ws[t.z];
        acc += __logf(fmaxf(x3, CLIP_V)) * ws[t.w];
    }

    const float b = block_reduce_sum(acc);
    if (threadIdx.x == 0) partial[blockIdx.x] = b;
}

__global__ __launch_bounds__(THREADS)
void logloss_final(const float* __restrict__ partial, float* __restrict__ out) {
    float v = 0.0f;
    for (int i = threadIdx.x; i < BLOCKS; i += THREADS) v += partial[i];
    const float s = block_reduce_sum(v);
    if (threadIdx.x == 0) out[0] = -s / (float)N_ROWS;
}

extern "C" void kernel_launch(void* const* d_in, const int* in_sizes, int n_in,
                              void* d_out, int out_size, void* d_ws, size_t ws_size,
                              hipStream_t stream) {
    const float* inp = (const float*)d_in[0];
    const int* tgt = (const int*)d_in[1];
    const float* w = (const float*)d_in[2];
    float* out = (float*)d_out;
    float* partial = (float*)d_ws; // needs BLOCKS * 4 bytes

    logloss_partial<<<BLOCKS, THREADS, 0, stream>>>(inp, tgt, w, partial);
    logloss_final<<<1, THREADS, 0, stream>>>(partial, out);
}

// Round 2
// 312.873 us; speedup vs baseline: 1.0051x; 1.0051x over previous
//
#include <hip/hip_runtime.h>

static constexpr int N_ROWS = 524288;
static constexpr int C_COLS = 128;
static constexpr float CLIP_V = 1e-10f;
static constexpr int BLOCKS = 2048;   // 524288 threads = 1 row/thread, 32 waves/CU
static constexpr int THREADS = 256;

__device__ __forceinline__ float block_reduce_sum(float v) {
    // 64-lane wave reduction (CDNA wave = 64)
    #pragma unroll
    for (int off = 32; off > 0; off >>= 1)
        v += __shfl_down(v, off, 64);
    __shared__ float s[THREADS / 64];
    const int lane = threadIdx.x & 63;
    const int wave = threadIdx.x >> 6;
    if (lane == 0) s[wave] = v;
    __syncthreads();
    if (wave == 0) {
        v = (lane < THREADS / 64) ? s[lane] : 0.0f;
        #pragma unroll
        for (int off = (THREADS / 64) / 2; off > 0; off >>= 1)
            v += __shfl_down(v, off, 64);
    }
    return v; // valid in threadIdx.x == 0
}

__global__ __launch_bounds__(THREADS)
void logloss_partial(const float* __restrict__ inp,
                     const int* __restrict__ tgt,
                     const float* __restrict__ w,
                     float* __restrict__ partial) {
    // stage weight[128] in LDS (512 B)
    __shared__ float ws[C_COLS];
    for (int j = threadIdx.x; j < C_COLS; j += THREADS) ws[j] = w[j];
    __syncthreads();

    const int tid = blockIdx.x * THREADS + threadIdx.x;
    const int stride = gridDim.x * THREADS;

    float acc = 0.0f; // sum of log(clip(x)) * w (negated at the end)
    for (int i = tid; i < N_ROWS; i += stride) {
        const int t = tgt[i];                          // coalesced 4B/lane
        const float x = inp[(size_t)i * C_COLS + t];   // one 4B gather per row
        acc += __logf(fmaxf(x, CLIP_V)) * ws[t];
    }

    const float b = block_reduce_sum(acc);
    if (threadIdx.x == 0) partial[blockIdx.x] = b;
}

__global__ __launch_bounds__(THREADS)
void logloss_final(const float* __restrict__ partial, float* __restrict__ out) {
    float v = 0.0f;
    for (int i = threadIdx.x; i < BLOCKS; i += THREADS) v += partial[i];
    const float s = block_reduce_sum(v);
    if (threadIdx.x == 0) out[0] = -s / (float)N_ROWS;
}

extern "C" void kernel_launch(void* const* d_in, const int* in_sizes, int n_in,
                              void* d_out, int out_size, void* d_ws, size_t ws_size,
                              hipStream_t stream) {
    const float* inp = (const float*)d_in[0];
    const int* tgt = (const int*)d_in[1];
    const float* w = (const float*)d_in[2];
    float* out = (float*)d_out;
    float* partial = (float*)d_ws; // BLOCKS * 4 bytes

    logloss_partial<<<BLOCKS, THREADS, 0, stream>>>(inp, tgt, w, partial);
    logloss_final<<<1, THREADS, 0, stream>>>(partial, out);
}